// Round 3
// baseline (112.720 us; speedup 1.0000x reference)
//
#include <hip/hip_runtime.h>
#include <math.h>

#define NB 32    // batch
#define NS 128   // steps
#define NI 256   // in_dim
#define NC 128   // num capsules
#define ND 64    // dim capsule

#define L4 9.210340371976184f  // ln(10000)

// ---------------------------------------------------------------------------
// k_prep v3:
//   blocks [0,1024):  M[b,s,d] = sum_i u*W ; U[b,s] = sum_i u
//     - u row staged in LDS via one float4/lane
//     - lane = (ih, dq): 4-way i-split x 16 d-quads; W read as float4
//       (VMEM instrs/thread 256 -> 64); partials combined via shfl_xor(16,32)
//     - U[row] via wave shuffle-reduce of the staged float4s
//   blocks [1024,1056): PE1[n][d]
// ---------------------------------------------------------------------------
__global__ __launch_bounds__(256) void k_prep(const float* __restrict__ u,
                                              const float* __restrict__ W,
                                              float* __restrict__ M,
                                              float* __restrict__ U,
                                              float* __restrict__ PE1) {
    int blk = blockIdx.x;
    int t = threadIdx.x;
    if (blk < 1024) {
        __shared__ float us[4][NI];
        int g = t >> 6, lane = t & 63;
        int row = blk * 4 + g;                       // b*NS + s
        float4 v4 = ((const float4*)(u + (size_t)row * NI))[lane];
        ((float4*)us[g])[lane] = v4;
        float rs = v4.x + v4.y + v4.z + v4.w;
#pragma unroll
        for (int o = 32; o > 0; o >>= 1) rs += __shfl_xor(rs, o);
        if (lane == 0) U[row] = rs;

        int ih = lane >> 4, dq = lane & 15;
        int base = ih * 64;
        const float4* W4 = (const float4*)W;         // [NI][16] quads
        float4 acc = make_float4(0.f, 0.f, 0.f, 0.f);
#pragma unroll 8
        for (int ii = 0; ii < 64; ++ii) {
            float uu = us[g][base + ii];
            float4 w4 = W4[(base + ii) * 16 + dq];
            acc.x = fmaf(uu, w4.x, acc.x);
            acc.y = fmaf(uu, w4.y, acc.y);
            acc.z = fmaf(uu, w4.z, acc.z);
            acc.w = fmaf(uu, w4.w, acc.w);
        }
        // combine the 4 ih partials (lanes xor 16, 32)
#pragma unroll
        for (int o = 16; o <= 32; o <<= 1) {
            acc.x += __shfl_xor(acc.x, o);
            acc.y += __shfl_xor(acc.y, o);
            acc.z += __shfl_xor(acc.z, o);
            acc.w += __shfl_xor(acc.w, o);
        }
        if (ih == 0) ((float4*)M)[row * 16 + dq] = acc;
    } else {
        int idx = (blk - 1024) * 256 + t;   // 8192 elems, [n][d]
        int n = idx >> 6, d = idx & 63;
        float ang = (float)n * __expf(-L4 * (float)(d >> 1) * (1.f / 32.f));
        float sv, cv;
        __sincosf(ang, &sv, &cv);
        PE1[idx] = (d & 1) ? cv : sv;
    }
}

// ---------------------------------------------------------------------------
// kR v7: one routing iteration, block = (2 batches, 2 capsules).
// 256 threads, ~43 KB LDS, grid = 1024, launch_bounds(256,2).
// M float4 loads (the L2-BW limiter) are shared across BOTH capsules ->
// M traffic per call halves vs v6 (128 MB -> 64 MB). Rotation recurrence
// still shared across the b-pair. Thread (sq=t>>4, dq=t&15) owns
// s in [sq*8, sq*8+8) x d-quad dq for 2b x 2n.
//   staging: cs4[s] = c for (nh,bh) 4-combos packed; Us[s][bh];
//            T2[bh][nh] = sum_s c*U via per-wave shfl.
//   pass 1: v{A,B}{0,1}[i] = M + pe2(rotation); acc += c*v (4 combos);
//           shfl reduce over sq-chunks; 64-lane tail: +pe1*T2, squash, PUu.
//   pass 2: dot(v, outs4) -> red2[bh][nh][s*17+dq]; 256 threads sum 16
//           partials + PUu*U per (bh,nh); coalesced bl stores.
// ---------------------------------------------------------------------------
__global__ __launch_bounds__(256, 2) void kR(const float* __restrict__ M,
                                             const float* __restrict__ U,
                                             const float* __restrict__ PE1,
                                             const float* __restrict__ cg,
                                             const float* __restrict__ mask,
                                             float* __restrict__ og,
                                             float* __restrict__ bl,
                                             int first, int last) {
    int bp = blockIdx.x;                // (b-pair)*64 + n-pair
    int n0 = (bp & 63) * 2;
    int b0 = (bp >> 6) * 2;
    int t  = threadIdx.x;

    __shared__ float4 cs4[NS];          // 2 KB  [s] = {n0b0, n0b1, n1b0, n1b1}
    __shared__ float  Us[NS][2];        // 1 KB
    __shared__ float4 redw[2][2][4][16];// 4 KB  [bh][nh][w][q]
    __shared__ float4 outs4[2][2][16];  // 1 KB  [bh][nh][q]
    __shared__ float  tpar[2][2][2];    // [bh][nh][wavehalf]
    __shared__ float  sc2[2][2][2];     // [bh][nh][{scale, PUu}]
    __shared__ float  red2[2][2][NS * 17]; // 34816 B

    // ---- staging: c, U, and T2[bh][nh] = sum_s c*U ----
    {
        int bh = t >> 7, s = t & 127;
        int b = b0 + bh;
        float uu = U[b * NS + s];
        float cv0, cv1;
        if (first) {
            float mv = mask[b * NS + s] * (1.f / 128.f);
            cv0 = mv; cv1 = mv;
        } else {
            cv0 = cg[(b * NC + n0) * NS + s];
            cv1 = cg[(b * NC + n0 + 1) * NS + s];
        }
        ((float*)&cs4[s])[bh]     = cv0;   // [nh*2 + bh]
        ((float*)&cs4[s])[2 + bh] = cv1;
        Us[s][bh] = uu;
        float p0 = cv0 * uu, p1 = cv1 * uu;
#pragma unroll
        for (int o = 32; o > 0; o >>= 1) {
            p0 += __shfl_xor(p0, o);
            p1 += __shfl_xor(p1, o);
        }
        if ((t & 63) == 0) {
            tpar[bh][0][(t >> 6) & 1] = p0;
            tpar[bh][1][(t >> 6) & 1] = p1;
        }
    }

    // prefetch PE1 fragment for the squash tail (latency hides under pass 1)
    float4 p14;
    if (t < 64) {
        int nh = (t >> 4) & 1, q = t & 15;
        p14 = ((const float4*)PE1)[(n0 + nh) * 16 + q];
    }

    int dq = t & 15, sq = t >> 4;
    int s0 = sq * 8;
    // pe2 frequencies for (n0, dq) and (n0+1, dq) — each shared across b-pair
    int k20 = n0 * 32 + dq * 2;
    int k21 = (n0 + 1) * 32 + dq * 2;
    float g00 = __expf(-L4 * (float)k20 * (1.f / 4096.f));
    float g01 = __expf(-L4 * (float)(k20 + 1) * (1.f / 4096.f));
    float g10 = __expf(-L4 * (float)k21 * (1.f / 4096.f));
    float g11 = __expf(-L4 * (float)(k21 + 1) * (1.f / 4096.f));
    float sa0, ca0, sb0, cb0, sa1, ca1, sb1, cb1;
    __sincosf((float)s0 * g00, &sa0, &ca0);
    __sincosf((float)s0 * g01, &sb0, &cb0);
    __sincosf((float)s0 * g10, &sa1, &ca1);
    __sincosf((float)s0 * g11, &sb1, &cb1);
    float sg00, cg00, sg01, cg01, sg10, cg10, sg11, cg11;
    __sincosf(g00, &sg00, &cg00);
    __sincosf(g01, &sg01, &cg01);
    __sincosf(g10, &sg10, &cg10);
    __sincosf(g11, &sg11, &cg11);
    __syncthreads();

    // ---- pass 1 ----
    const float4* M4a = (const float4*)(M + (size_t)(b0 * NS) * ND) + dq;
    const float4* M4b = M4a + NS * 16;
    float4 vA0[8], vB0[8], vA1[8], vB1[8];
    float4 accA0 = make_float4(0.f, 0.f, 0.f, 0.f);
    float4 accB0 = make_float4(0.f, 0.f, 0.f, 0.f);
    float4 accA1 = make_float4(0.f, 0.f, 0.f, 0.f);
    float4 accB1 = make_float4(0.f, 0.f, 0.f, 0.f);
#pragma unroll
    for (int i = 0; i < 8; ++i) {
        int s = s0 + i;
        float4 m0 = M4a[s * 16];
        float4 m1 = M4b[s * 16];
        float4 cc = cs4[s];          // {n0b0, n0b1, n1b0, n1b1}
        float4 u00, u10, u01, u11;   // u{bh}{nh}
        u00.x = m0.x + sa0; u00.y = m0.y + ca0; u00.z = m0.z + sb0; u00.w = m0.w + cb0;
        u10.x = m1.x + sa0; u10.y = m1.y + ca0; u10.z = m1.z + sb0; u10.w = m1.w + cb0;
        u01.x = m0.x + sa1; u01.y = m0.y + ca1; u01.z = m0.z + sb1; u01.w = m0.w + cb1;
        u11.x = m1.x + sa1; u11.y = m1.y + ca1; u11.z = m1.z + sb1; u11.w = m1.w + cb1;
        vA0[i] = u00; vB0[i] = u10; vA1[i] = u01; vB1[i] = u11;
        accA0.x = fmaf(cc.x, u00.x, accA0.x);
        accA0.y = fmaf(cc.x, u00.y, accA0.y);
        accA0.z = fmaf(cc.x, u00.z, accA0.z);
        accA0.w = fmaf(cc.x, u00.w, accA0.w);
        accB0.x = fmaf(cc.y, u10.x, accB0.x);
        accB0.y = fmaf(cc.y, u10.y, accB0.y);
        accB0.z = fmaf(cc.y, u10.z, accB0.z);
        accB0.w = fmaf(cc.y, u10.w, accB0.w);
        accA1.x = fmaf(cc.z, u01.x, accA1.x);
        accA1.y = fmaf(cc.z, u01.y, accA1.y);
        accA1.z = fmaf(cc.z, u01.z, accA1.z);
        accA1.w = fmaf(cc.z, u01.w, accA1.w);
        accB1.x = fmaf(cc.w, u11.x, accB1.x);
        accB1.y = fmaf(cc.w, u11.y, accB1.y);
        accB1.z = fmaf(cc.w, u11.z, accB1.z);
        accB1.w = fmaf(cc.w, u11.w, accB1.w);
        // rotate all four frequency pairs to s+1
        float ns, nc;
        ns = fmaf(sa0, cg00, ca0 * sg00); nc = fmaf(ca0, cg00, -sa0 * sg00); sa0 = ns; ca0 = nc;
        ns = fmaf(sb0, cg01, cb0 * sg01); nc = fmaf(cb0, cg01, -sb0 * sg01); sb0 = ns; cb0 = nc;
        ns = fmaf(sa1, cg10, ca1 * sg10); nc = fmaf(ca1, cg10, -sa1 * sg10); sa1 = ns; ca1 = nc;
        ns = fmaf(sb1, cg11, cb1 * sg11); nc = fmaf(cb1, cg11, -sb1 * sg11); sb1 = ns; cb1 = nc;
    }
    // reduce the 4 sq-chunks within each wave (lanes xor 16, 32)
#pragma unroll
    for (int o = 16; o <= 32; o <<= 1) {
        accA0.x += __shfl_xor(accA0.x, o); accA0.y += __shfl_xor(accA0.y, o);
        accA0.z += __shfl_xor(accA0.z, o); accA0.w += __shfl_xor(accA0.w, o);
        accB0.x += __shfl_xor(accB0.x, o); accB0.y += __shfl_xor(accB0.y, o);
        accB0.z += __shfl_xor(accB0.z, o); accB0.w += __shfl_xor(accB0.w, o);
        accA1.x += __shfl_xor(accA1.x, o); accA1.y += __shfl_xor(accA1.y, o);
        accA1.z += __shfl_xor(accA1.z, o); accA1.w += __shfl_xor(accA1.w, o);
        accB1.x += __shfl_xor(accB1.x, o); accB1.y += __shfl_xor(accB1.y, o);
        accB1.z += __shfl_xor(accB1.z, o); accB1.w += __shfl_xor(accB1.w, o);
    }
    if ((t & 48) == 0) {
        int w = t >> 6;
        redw[0][0][w][dq] = accA0;
        redw[1][0][w][dq] = accB0;
        redw[0][1][w][dq] = accA1;
        redw[1][1][w][dq] = accB1;
    }
    __syncthreads();

    // ---- combine + squash (wave 0, 64 lanes: 16 per (bh,nh) combo) ----
    if (t < 64) {
        int combo = t >> 4, q = t & 15;
        int bh = combo >> 1, nh = combo & 1;
        float4 r0 = redw[bh][nh][0][q], r1 = redw[bh][nh][1][q];
        float4 r2 = redw[bh][nh][2][q], r3 = redw[bh][nh][3][q];
        float4 o;
        o.x = r0.x + r1.x + r2.x + r3.x;
        o.y = r0.y + r1.y + r2.y + r3.y;
        o.z = r0.z + r1.z + r2.z + r3.z;
        o.w = r0.w + r1.w + r2.w + r3.w;
        float T2 = tpar[bh][nh][0] + tpar[bh][nh][1];
        o.x = fmaf(p14.x, T2, o.x);
        o.y = fmaf(p14.y, T2, o.y);
        o.z = fmaf(p14.z, T2, o.z);
        o.w = fmaf(p14.w, T2, o.w);
        outs4[bh][nh][q] = o;
        float ssq = o.x * o.x + o.y * o.y + o.z * o.z + o.w * o.w;
        float ppu = o.x * p14.x + o.y * p14.y + o.z * p14.z + o.w * p14.w;
#pragma unroll
        for (int o2 = 1; o2 <= 8; o2 <<= 1) {   // stays within 16-lane group
            ssq += __shfl_xor(ssq, o2);
            ppu += __shfl_xor(ppu, o2);
        }
        if (q == 0) {
            sc2[bh][nh][0] = ssq / (1.f + ssq) * rsqrtf(ssq + 1e-7f);
            sc2[bh][nh][1] = ppu;
        }
    }
    __syncthreads();

    if (last) {
        if (t < 64) {
            int combo = t >> 4, q = t & 15;
            int bh = combo >> 1, nh = combo & 1;
            float sc = sc2[bh][nh][0];
            float4 o = outs4[bh][nh][q];
            o.x *= sc; o.y *= sc; o.z *= sc; o.w *= sc;
            ((float4*)og)[((b0 + bh) * NC + n0 + nh) * 16 + q] = o;
        }
        return;
    }

    // ---- pass 2: bl[s] = scale*(sum_d outp*(M+pe2) + PUu*U[s]) ----
    float4 oA0 = outs4[0][0][dq], oB0 = outs4[1][0][dq];
    float4 oA1 = outs4[0][1][dq], oB1 = outs4[1][1][dq];
#pragma unroll
    for (int i = 0; i < 8; ++i) {
        int s = s0 + i;
        float4 v;
        v = vA0[i];
        red2[0][0][s * 17 + dq] = v.x * oA0.x + v.y * oA0.y + v.z * oA0.z + v.w * oA0.w;
        v = vB0[i];
        red2[1][0][s * 17 + dq] = v.x * oB0.x + v.y * oB0.y + v.z * oB0.z + v.w * oB0.w;
        v = vA1[i];
        red2[0][1][s * 17 + dq] = v.x * oA1.x + v.y * oA1.y + v.z * oA1.z + v.w * oA1.w;
        v = vB1[i];
        red2[1][1][s * 17 + dq] = v.x * oB1.x + v.y * oB1.y + v.z * oB1.z + v.w * oB1.w;
    }
    __syncthreads();
    {
        int bh = t >> 7, s = t & 127;
        float uu = Us[s][bh];
#pragma unroll
        for (int nh = 0; nh < 2; ++nh) {
            const float* r = &red2[bh][nh][s * 17];
            float sum = 0.f;
#pragma unroll
            for (int q = 0; q < 16; ++q) sum += r[q];
            bl[((b0 + bh) * NC + n0 + nh) * NS + s] =
                sc2[bh][nh][0] * (sum + sc2[bh][nh][1] * uu);
        }
    }
}

// ---------------------------------------------------------------------------
// kS: softmax over n for each (b,s); c[b,n,s] = softmax_n(bl[b,n,s])*mask.
// bl/c layout [b][n][s]. Block = (b, 16-s tile), 256 thr. grid = 256.
// ---------------------------------------------------------------------------
__global__ __launch_bounds__(256) void kS(const float* __restrict__ bl,
                                          const float* __restrict__ mask,
                                          float* __restrict__ c) {
    int blk = blockIdx.x;
    int b = blk >> 3, s0 = (blk & 7) * 16;
    int t = threadIdx.x;

    __shared__ float tl[NC][17];
    __shared__ float pr[16][17];
    __shared__ float ps[16][17];
    __shared__ float itot[16], msk[16];

    if (t < 16) msk[t] = mask[b * NS + s0 + t];
#pragma unroll
    for (int i = 0; i < 8; ++i) {
        int idx = i * 256 + t;
        int n = idx >> 4, si = idx & 15;
        tl[n][si] = bl[(b * NC + n) * NS + s0 + si];
    }
    __syncthreads();

    int si = t & 15, ch = t >> 4;      // 16 chunks x 8 n each
    float mx = -1e30f;
#pragma unroll
    for (int j = 0; j < 8; ++j) mx = fmaxf(mx, tl[ch * 8 + j][si]);
    pr[ch][si] = mx;
    __syncthreads();

    mx = pr[0][si];
#pragma unroll
    for (int jc = 1; jc < 16; ++jc) mx = fmaxf(mx, pr[jc][si]);
    float sm = 0.f;
#pragma unroll
    for (int j = 0; j < 8; ++j) {
        float e = __expf(tl[ch * 8 + j][si] - mx);
        tl[ch * 8 + j][si] = e;       // owner-exclusive rows: no race
        sm += e;
    }
    ps[ch][si] = sm;
    __syncthreads();

    if (t < 16) {
        float tot = 0.f;
#pragma unroll
        for (int jc = 0; jc < 16; ++jc) tot += ps[jc][t];
        itot[t] = msk[t] / tot;
    }
    __syncthreads();

#pragma unroll
    for (int i = 0; i < 8; ++i) {
        int idx = i * 256 + t;
        int n = idx >> 4, sj = idx & 15;
        c[(b * NC + n) * NS + s0 + sj] = tl[n][sj] * itot[sj];
    }
}

// ---------------------------------------------------------------------------
extern "C" void kernel_launch(void* const* d_in, const int* in_sizes, int n_in,
                              void* d_out, int out_size, void* d_ws, size_t ws_size,
                              hipStream_t stream) {
    const float* u    = (const float*)d_in[0];  // (32,128,256)
    const float* mask = (const float*)d_in[1];  // (32,128)
    const float* W    = (const float*)d_in[2];  // (1,256,64)
    float* out = (float*)d_out;                 // (32,128,64) = [b][n][d]

    float* ws  = (float*)d_ws;
    float* M   = ws;                            // 262144
    float* U   = M + NB * NS * ND;              // 4096
    float* PE1 = U + NB * NS;                   // 8192
    float* c   = PE1 + NC * ND;                 // 524288  [b][n][s]
    float* bl  = c + NB * NC * NS;              // 524288  [b][n][s]

    k_prep<<<1056, 256, 0, stream>>>(u, W, M, U, PE1);

    // iter 0 (uniform c = mask/128) -> logits bl
    kR<<<1024, 256, 0, stream>>>(M, U, PE1, c, mask, out, bl, 1, 0);
    kS<<<NB * 8, 256, 0, stream>>>(bl, mask, c);
    // iter 1 -> logits bl
    kR<<<1024, 256, 0, stream>>>(M, U, PE1, c, mask, out, bl, 0, 0);
    kS<<<NB * 8, 256, 0, stream>>>(bl, mask, c);
    // iter 2 (final) -> d_out
    kR<<<1024, 256, 0, stream>>>(M, U, PE1, c, mask, out, bl, 0, 1);
}

// Round 4
// 99.611 us; speedup vs baseline: 1.1316x; 1.1316x over previous
//
#include <hip/hip_runtime.h>
#include <math.h>

#define NB 32    // batch
#define NS 128   // steps
#define NI 256   // in_dim
#define NC 128   // num capsules
#define ND 64    // dim capsule

#define L4 9.210340371976184f  // ln(10000)

// ---------------------------------------------------------------------------
// k_prep v4:
//   blocks [0,256):  16 M-rows per block. W amortized across rows via LDS:
//     - stage u rows (16 KB) once; U[row] via 16-lane shfl reduce of staging
//       partials (thread t's 4 consecutive float4 all belong to row t>>4)
//     - stage W in two 32 KB phases (i in [0,128), [128,256)); total 48 KB LDS
//     - thread = (wave w, rh=lane>>5, dp=lane&31): rows {4w+2rh, 4w+2rh+1},
//       d-pair {2dp, 2dp+1}. Inner i: 1 ds_read_b64 (W, conflict-free) +
//       2 broadcast ds_read_b32 (u, 2-way = free) + 4 fma.
//     W L2 traffic: 256 blocks x 64 KB = 16 MB (was 4096 waves x 64 KB = 256 MB).
//   blocks [256,288): PE1[n][d]
// ---------------------------------------------------------------------------
__global__ __launch_bounds__(256) void k_prep(const float* __restrict__ u,
                                              const float* __restrict__ W,
                                              float* __restrict__ M,
                                              float* __restrict__ U,
                                              float* __restrict__ PE1) {
    int blk = blockIdx.x;
    int t = threadIdx.x;
    if (blk < 256) {
        __shared__ float us[16][NI];        // 16 KB
        __shared__ float ws[128 * ND];      // 32 KB (one W i-phase)
        int r0 = blk * 16;

        // ---- stage u (16 rows x 256 floats) + U row sums ----
        {
            const float4* u4 = (const float4*)(u + (size_t)r0 * NI);
            float4* us4 = (float4*)us;
            float up = 0.f;
#pragma unroll
            for (int j = 0; j < 4; ++j) {
                int fi = t * 4 + j;          // 4 consecutive f4 -> same row (t>>4)
                float4 v = u4[fi];
                us4[fi] = v;
                up += v.x + v.y + v.z + v.w;
            }
#pragma unroll
            for (int o = 1; o <= 8; o <<= 1) up += __shfl_xor(up, o);
            if ((t & 15) == 0) U[r0 + (t >> 4)] = up;
        }

        int lane = t & 63, w = t >> 6;
        int dp = lane & 31;                  // d-pair index (d = 2dp, 2dp+1)
        int rh = lane >> 5;
        int rA = w * 4 + rh * 2, rB = rA + 1;
        float2 accA = make_float2(0.f, 0.f), accB = make_float2(0.f, 0.f);
        const float4* W4 = (const float4*)W; // [NI][16] quads

        for (int p = 0; p < 2; ++p) {
            __syncthreads();                 // us visible (p=0) / ws drained (p=1)
            {
                float4* ws4 = (float4*)ws;
#pragma unroll
                for (int j = 0; j < 8; ++j) {
                    int fi = t + 256 * j;    // coalesced copy of 2048 f4
                    ws4[fi] = W4[p * 2048 + fi];
                }
            }
            __syncthreads();
            int ibase = p * 128;
#pragma unroll 8
            for (int ii = 0; ii < 128; ++ii) {
                float2 wv = *(const float2*)&ws[ii * ND + dp * 2];
                float ua = us[rA][ibase + ii];
                float ub = us[rB][ibase + ii];
                accA.x = fmaf(ua, wv.x, accA.x);
                accA.y = fmaf(ua, wv.y, accA.y);
                accB.x = fmaf(ub, wv.x, accB.x);
                accB.y = fmaf(ub, wv.y, accB.y);
            }
        }
        float2* M2 = (float2*)M;
        M2[(size_t)(r0 + rA) * 32 + dp] = accA;
        M2[(size_t)(r0 + rB) * 32 + dp] = accB;
    } else {
        int idx = (blk - 256) * 256 + t;     // 8192 elems, [n][d]
        int n = idx >> 6, d = idx & 63;
        float ang = (float)n * __expf(-L4 * (float)(d >> 1) * (1.f / 32.f));
        float sv, cv;
        __sincosf(ang, &sv, &cv);
        PE1[idx] = (d & 1) ? cv : sv;
    }
}

// ---------------------------------------------------------------------------
// kR v6.1 (proven, Round-1): one routing iteration, block = (2 batches, 1 n).
// 256 threads, ~22 KB LDS, grid = 2048. Thread (sq=t>>4, dq=t&15) owns
// s in [sq*8, sq*8+8) x d-quad dq for BOTH batches: the pe2 rotation
// recurrence (identical for both b's at fixed (n,dq)) is computed ONCE and
// consumed twice. c pairs prefetched as 4x ds_read_b128 before pass 1;
// PE1 float4 for the squash tail loaded before pass 1 (latency hidden).
// ---------------------------------------------------------------------------
__global__ __launch_bounds__(256, 4) void kR(const float* __restrict__ M,
                                             const float* __restrict__ U,
                                             const float* __restrict__ PE1,
                                             const float* __restrict__ cg,
                                             const float* __restrict__ mask,
                                             float* __restrict__ og,
                                             float* __restrict__ bl,
                                             int first, int last) {
    int bp = blockIdx.x;                // (b-pair)*128 + n
    int n  = bp & 127;
    int b0 = (bp >> 7) * 2;
    int t  = threadIdx.x;

    __shared__ float  cs[NS][2];        // 1 KB  (c for b0, b0+1 packed)
    __shared__ float  Us[NS][2];        // 1 KB
    __shared__ float4 redw[2][4][16];   // 2 KB
    __shared__ float4 outs4[2][16];     // 512 B
    __shared__ float  tpar[2][2];
    __shared__ float  sc2[2][2];        // [bh][{scale, PUu}]
    __shared__ float  red2[2][NS * 17]; // 17408 B

    // ---- staging: c, U, and T2[bh] = sum_s c*U (one wave per 64 s) ----
    {
        int bh = t >> 7, s = t & 127;
        int b = b0 + bh;
        float uu = U[b * NS + s];
        float cv = first ? mask[b * NS + s] * (1.f / 128.f)
                         : cg[(b * NC + n) * NS + s];
        cs[s][bh] = cv;
        Us[s][bh] = uu;
        float p = cv * uu;
#pragma unroll
        for (int o = 32; o > 0; o >>= 1) p += __shfl_xor(p, o);
        if ((t & 63) == 0) tpar[bh][(t >> 6) & 1] = p;
    }

    // prefetch PE1 fragment for the squash tail (latency hides under pass 1)
    float4 p14;
    if (t < 32) p14 = ((const float4*)PE1)[n * 16 + (t & 15)];

    int dq = t & 15, sq = t >> 4;
    int s0 = sq * 8;
    // pe2 frequencies for (n, dq) — shared by both batches
    int k2 = n * 32 + dq * 2;
    float g0 = __expf(-L4 * (float)k2 * (1.f / 4096.f));
    float g1 = __expf(-L4 * (float)(k2 + 1) * (1.f / 4096.f));
    float sa = __sinf((float)s0 * g0), ca = __cosf((float)s0 * g0);
    float sb = __sinf((float)s0 * g1), cb = __cosf((float)s0 * g1);
    float sg0 = __sinf(g0), cg0 = __cosf(g0);
    float sg1 = __sinf(g1), cg1 = __cosf(g1);
    __syncthreads();

    // prefetch the 8 c-pairs for this thread's s-range (4x ds_read_b128)
    float4 cc4[4];
    {
        const float4* csp = (const float4*)&cs[s0][0];
        cc4[0] = csp[0]; cc4[1] = csp[1]; cc4[2] = csp[2]; cc4[3] = csp[3];
    }

    // ---- pass 1 ----
    const float4* M4a = (const float4*)(M + (size_t)(b0 * NS) * ND) + dq;
    const float4* M4b = M4a + NS * 16;
    float4 va[8], vb[8];
    float4 acc0 = make_float4(0.f, 0.f, 0.f, 0.f);
    float4 acc1 = make_float4(0.f, 0.f, 0.f, 0.f);
#pragma unroll
    for (int i = 0; i < 8; ++i) {
        int s = s0 + i;
        float4 m0 = M4a[s * 16];
        float4 m1 = M4b[s * 16];
        float2 cc = ((const float2*)cc4)[i];
        float4 u0, u1;
        u0.x = m0.x + sa; u0.y = m0.y + ca; u0.z = m0.z + sb; u0.w = m0.w + cb;
        u1.x = m1.x + sa; u1.y = m1.y + ca; u1.z = m1.z + sb; u1.w = m1.w + cb;
        va[i] = u0; vb[i] = u1;
        acc0.x = fmaf(cc.x, u0.x, acc0.x);
        acc0.y = fmaf(cc.x, u0.y, acc0.y);
        acc0.z = fmaf(cc.x, u0.z, acc0.z);
        acc0.w = fmaf(cc.x, u0.w, acc0.w);
        acc1.x = fmaf(cc.y, u1.x, acc1.x);
        acc1.y = fmaf(cc.y, u1.y, acc1.y);
        acc1.z = fmaf(cc.y, u1.z, acc1.z);
        acc1.w = fmaf(cc.y, u1.w, acc1.w);
        // rotate both frequency pairs to s+1
        float nsa = fmaf(sa, cg0, ca * sg0);
        float nca = fmaf(ca, cg0, -sa * sg0);
        sa = nsa; ca = nca;
        float nsb = fmaf(sb, cg1, cb * sg1);
        float ncb = fmaf(cb, cg1, -sb * sg1);
        sb = nsb; cb = ncb;
    }
    // reduce the 4 sq-chunks within each wave (lanes xor 16, 32)
#pragma unroll
    for (int o = 16; o <= 32; o <<= 1) {
        acc0.x += __shfl_xor(acc0.x, o); acc0.y += __shfl_xor(acc0.y, o);
        acc0.z += __shfl_xor(acc0.z, o); acc0.w += __shfl_xor(acc0.w, o);
        acc1.x += __shfl_xor(acc1.x, o); acc1.y += __shfl_xor(acc1.y, o);
        acc1.z += __shfl_xor(acc1.z, o); acc1.w += __shfl_xor(acc1.w, o);
    }
    if ((t & 48) == 0) {
        int w = t >> 6;
        redw[0][w][dq] = acc0;
        redw[1][w][dq] = acc1;
    }
    __syncthreads();

    // ---- combine + squash (wave 0, lanes 0-31: 16 lanes per bh) ----
    if (t < 32) {
        int bh = t >> 4, q = t & 15;
        float4 r0 = redw[bh][0][q], r1 = redw[bh][1][q];
        float4 r2 = redw[bh][2][q], r3 = redw[bh][3][q];
        float4 o;
        o.x = r0.x + r1.x + r2.x + r3.x;
        o.y = r0.y + r1.y + r2.y + r3.y;
        o.z = r0.z + r1.z + r2.z + r3.z;
        o.w = r0.w + r1.w + r2.w + r3.w;
        float T2 = tpar[bh][0] + tpar[bh][1];
        o.x = fmaf(p14.x, T2, o.x);
        o.y = fmaf(p14.y, T2, o.y);
        o.z = fmaf(p14.z, T2, o.z);
        o.w = fmaf(p14.w, T2, o.w);
        outs4[bh][q] = o;
        float ssq = o.x * o.x + o.y * o.y + o.z * o.z + o.w * o.w;
        float ppu = o.x * p14.x + o.y * p14.y + o.z * p14.z + o.w * p14.w;
#pragma unroll
        for (int o2 = 1; o2 <= 8; o2 <<= 1) {   // stays within 16-lane group
            ssq += __shfl_xor(ssq, o2);
            ppu += __shfl_xor(ppu, o2);
        }
        if (q == 0) {
            sc2[bh][0] = ssq / (1.f + ssq) * rsqrtf(ssq + 1e-7f);
            sc2[bh][1] = ppu;
        }
    }
    __syncthreads();

    if (last) {
        if (t < 32) {
            int bh = t >> 4, q = t & 15;
            float sc = sc2[bh][0];
            float4 o = outs4[bh][q];
            o.x *= sc; o.y *= sc; o.z *= sc; o.w *= sc;
            ((float4*)og)[((b0 + bh) * NC + n) * 16 + q] = o;
        }
        return;
    }

    // ---- pass 2: bl[s] = scale*(sum_d outp*(M+pe2) + PUu*U[s]) ----
    float4 oa = outs4[0][dq], ob = outs4[1][dq];
#pragma unroll
    for (int i = 0; i < 8; ++i) {
        int s = s0 + i;
        float4 v0 = va[i], v1 = vb[i];
        red2[0][s * 17 + dq] = v0.x * oa.x + v0.y * oa.y + v0.z * oa.z + v0.w * oa.w;
        red2[1][s * 17 + dq] = v1.x * ob.x + v1.y * ob.y + v1.z * ob.z + v1.w * ob.w;
    }
    __syncthreads();
    {
        int bh = t >> 7, s = t & 127;
        const float* r = &red2[bh][s * 17];
        float sum = 0.f;
#pragma unroll
        for (int q = 0; q < 16; ++q) sum += r[q];
        bl[((b0 + bh) * NC + n) * NS + s] =
            sc2[bh][0] * (sum + sc2[bh][1] * Us[s][bh]);
    }
}

// ---------------------------------------------------------------------------
// kS: softmax over n for each (b,s); c[b,n,s] = softmax_n(bl[b,n,s])*mask.
// bl/c layout [b][n][s]. Block = (b, 16-s tile), 256 thr. grid = 256.
// ---------------------------------------------------------------------------
__global__ __launch_bounds__(256) void kS(const float* __restrict__ bl,
                                          const float* __restrict__ mask,
                                          float* __restrict__ c) {
    int blk = blockIdx.x;
    int b = blk >> 3, s0 = (blk & 7) * 16;
    int t = threadIdx.x;

    __shared__ float tl[NC][17];
    __shared__ float pr[16][17];
    __shared__ float ps[16][17];
    __shared__ float itot[16], msk[16];

    if (t < 16) msk[t] = mask[b * NS + s0 + t];
#pragma unroll
    for (int i = 0; i < 8; ++i) {
        int idx = i * 256 + t;
        int n = idx >> 4, si = idx & 15;
        tl[n][si] = bl[(b * NC + n) * NS + s0 + si];
    }
    __syncthreads();

    int si = t & 15, ch = t >> 4;      // 16 chunks x 8 n each
    float mx = -1e30f;
#pragma unroll
    for (int j = 0; j < 8; ++j) mx = fmaxf(mx, tl[ch * 8 + j][si]);
    pr[ch][si] = mx;
    __syncthreads();

    mx = pr[0][si];
#pragma unroll
    for (int jc = 1; jc < 16; ++jc) mx = fmaxf(mx, pr[jc][si]);
    float sm = 0.f;
#pragma unroll
    for (int j = 0; j < 8; ++j) {
        float e = __expf(tl[ch * 8 + j][si] - mx);
        tl[ch * 8 + j][si] = e;       // owner-exclusive rows: no race
        sm += e;
    }
    ps[ch][si] = sm;
    __syncthreads();

    if (t < 16) {
        float tot = 0.f;
#pragma unroll
        for (int jc = 0; jc < 16; ++jc) tot += ps[jc][t];
        itot[t] = msk[t] / tot;
    }
    __syncthreads();

#pragma unroll
    for (int i = 0; i < 8; ++i) {
        int idx = i * 256 + t;
        int n = idx >> 4, sj = idx & 15;
        c[(b * NC + n) * NS + s0 + sj] = tl[n][sj] * itot[sj];
    }
}

// ---------------------------------------------------------------------------
extern "C" void kernel_launch(void* const* d_in, const int* in_sizes, int n_in,
                              void* d_out, int out_size, void* d_ws, size_t ws_size,
                              hipStream_t stream) {
    const float* u    = (const float*)d_in[0];  // (32,128,256)
    const float* mask = (const float*)d_in[1];  // (32,128)
    const float* W    = (const float*)d_in[2];  // (1,256,64)
    float* out = (float*)d_out;                 // (32,128,64) = [b][n][d]

    float* ws  = (float*)d_ws;
    float* M   = ws;                            // 262144
    float* U   = M + NB * NS * ND;              // 4096
    float* PE1 = U + NB * NS;                   // 8192
    float* c   = PE1 + NC * ND;                 // 524288  [b][n][s]
    float* bl  = c + NB * NC * NS;              // 524288  [b][n][s]

    k_prep<<<288, 256, 0, stream>>>(u, W, M, U, PE1);

    // iter 0 (uniform c = mask/128) -> logits bl
    kR<<<2048, 256, 0, stream>>>(M, U, PE1, c, mask, out, bl, 1, 0);
    kS<<<NB * 8, 256, 0, stream>>>(bl, mask, c);
    // iter 1 -> logits bl
    kR<<<2048, 256, 0, stream>>>(M, U, PE1, c, mask, out, bl, 0, 0);
    kS<<<NB * 8, 256, 0, stream>>>(bl, mask, c);
    // iter 2 (final) -> d_out
    kR<<<2048, 256, 0, stream>>>(M, U, PE1, c, mask, out, bl, 0, 1);
}

// Round 5
// 98.303 us; speedup vs baseline: 1.1467x; 1.0133x over previous
//
#include <hip/hip_runtime.h>
#include <math.h>

#define NB 32    // batch
#define NS 128   // steps
#define NI 256   // in_dim
#define NC 128   // num capsules
#define ND 64    // dim capsule

#define L4 9.210340371976184f  // ln(10000)

// ---------------------------------------------------------------------------
// k_prep v4 (proven R4):
//   blocks [0,256):  16 M-rows per block. W amortized across rows via LDS.
//   blocks [256,288): PE1[n][d]
// ---------------------------------------------------------------------------
__global__ __launch_bounds__(256) void k_prep(const float* __restrict__ u,
                                              const float* __restrict__ W,
                                              float* __restrict__ M,
                                              float* __restrict__ U,
                                              float* __restrict__ PE1) {
    int blk = blockIdx.x;
    int t = threadIdx.x;
    if (blk < 256) {
        __shared__ float us[16][NI];        // 16 KB
        __shared__ float ws[128 * ND];      // 32 KB (one W i-phase)
        int r0 = blk * 16;

        // ---- stage u (16 rows x 256 floats) + U row sums ----
        {
            const float4* u4 = (const float4*)(u + (size_t)r0 * NI);
            float4* us4 = (float4*)us;
            float up = 0.f;
#pragma unroll
            for (int j = 0; j < 4; ++j) {
                int fi = t * 4 + j;          // 4 consecutive f4 -> same row (t>>4)
                float4 v = u4[fi];
                us4[fi] = v;
                up += v.x + v.y + v.z + v.w;
            }
#pragma unroll
            for (int o = 1; o <= 8; o <<= 1) up += __shfl_xor(up, o);
            if ((t & 15) == 0) U[r0 + (t >> 4)] = up;
        }

        int lane = t & 63, w = t >> 6;
        int dp = lane & 31;                  // d-pair index (d = 2dp, 2dp+1)
        int rh = lane >> 5;
        int rA = w * 4 + rh * 2, rB = rA + 1;
        float2 accA = make_float2(0.f, 0.f), accB = make_float2(0.f, 0.f);
        const float4* W4 = (const float4*)W; // [NI][16] quads

        for (int p = 0; p < 2; ++p) {
            __syncthreads();                 // us visible (p=0) / ws drained (p=1)
            {
                float4* ws4 = (float4*)ws;
#pragma unroll
                for (int j = 0; j < 8; ++j) {
                    int fi = t + 256 * j;    // coalesced copy of 2048 f4
                    ws4[fi] = W4[p * 2048 + fi];
                }
            }
            __syncthreads();
            int ibase = p * 128;
#pragma unroll 8
            for (int ii = 0; ii < 128; ++ii) {
                float2 wv = *(const float2*)&ws[ii * ND + dp * 2];
                float ua = us[rA][ibase + ii];
                float ub = us[rB][ibase + ii];
                accA.x = fmaf(ua, wv.x, accA.x);
                accA.y = fmaf(ua, wv.y, accA.y);
                accB.x = fmaf(ub, wv.x, accB.x);
                accB.y = fmaf(ub, wv.y, accB.y);
            }
        }
        float2* M2 = (float2*)M;
        M2[(size_t)(r0 + rA) * 32 + dp] = accA;
        M2[(size_t)(r0 + rB) * 32 + dp] = accB;
    } else {
        int idx = (blk - 256) * 256 + t;     // 8192 elems, [n][d]
        int n = idx >> 6, d = idx & 63;
        float ang = (float)n * __expf(-L4 * (float)(d >> 1) * (1.f / 32.f));
        float sv, cv;
        __sincosf(ang, &sv, &cv);
        PE1[idx] = (d & 1) ? cv : sv;
    }
}

// ---------------------------------------------------------------------------
// kRed: per-(b,s) softmax statistics over n.
//   mx[b,s]   = max_n bl[b,n,s]
//   minv[b,s] = mask[b,s] / sum_n exp(bl[b,n,s] - mx)
// Block = (b, 32-s quarter), 256 thr = (nh=t>>5 8 n-groups x 16 n, si=t&31).
// Values kept in 16 regs -> single pass over bl. grid = 128.
// Replaces kS: writes 32 KB instead of 512 KB; the consumer kR computes
// c = exp(bl - mx)*minv inline during staging.
// ---------------------------------------------------------------------------
__global__ __launch_bounds__(256) void kRed(const float* __restrict__ bl,
                                            const float* __restrict__ mask,
                                            float* __restrict__ mx,
                                            float* __restrict__ minv) {
    int blk = blockIdx.x;
    int b = blk >> 2, s0 = (blk & 3) * 32;
    int t = threadIdx.x;
    int si = t & 31, nh = t >> 5;

    __shared__ float mxp[8][33];
    __shared__ float totp[8][33];

    float v[16];
    float m = -1e30f;
    const float* base = bl + (size_t)(b * NC + nh * 16) * NS + s0 + si;
#pragma unroll
    for (int j = 0; j < 16; ++j) {
        v[j] = base[j * NS];
        m = fmaxf(m, v[j]);
    }
    mxp[nh][si] = m;
    __syncthreads();

    float gm = mxp[0][si];
#pragma unroll
    for (int k = 1; k < 8; ++k) gm = fmaxf(gm, mxp[k][si]);
    float sm = 0.f;
#pragma unroll
    for (int j = 0; j < 16; ++j) sm += __expf(v[j] - gm);
    totp[nh][si] = sm;
    __syncthreads();

    if (t < 32) {   // nh==0 here, so this thread's gm is the full max for si=t
        float tot = 0.f;
#pragma unroll
        for (int k = 0; k < 8; ++k) tot += totp[k][t];
        mx[b * NS + s0 + t] = gm;
        minv[b * NS + s0 + t] = mask[b * NS + s0 + t] / tot;
    }
}

// ---------------------------------------------------------------------------
// kR v6.2: one routing iteration, block = (2 batches, 1 n).
// 256 threads, ~22 KB LDS, grid = 2048, launch_bounds(256,4).
// v6.2: c computed inline from bl + (mx, minv) during staging (kS removed).
// Race note: staging reads bl rows (b0,n),(b0+1,n); pass 2 writes the SAME
// rows, strictly after the staging read, and rows are block-exclusive.
// ---------------------------------------------------------------------------
__global__ __launch_bounds__(256, 4) void kR(const float* __restrict__ M,
                                             const float* __restrict__ U,
                                             const float* __restrict__ PE1,
                                             const float* __restrict__ mxg,
                                             const float* __restrict__ minvg,
                                             const float* __restrict__ mask,
                                             float* __restrict__ og,
                                             float* __restrict__ bl,
                                             int first, int last) {
    int bp = blockIdx.x;                // (b-pair)*128 + n
    int n  = bp & 127;
    int b0 = (bp >> 7) * 2;
    int t  = threadIdx.x;

    __shared__ float  cs[NS][2];        // 1 KB  (c for b0, b0+1 packed)
    __shared__ float  Us[NS][2];        // 1 KB
    __shared__ float4 redw[2][4][16];   // 2 KB
    __shared__ float4 outs4[2][16];     // 512 B
    __shared__ float  tpar[2][2];
    __shared__ float  sc2[2][2];        // [bh][{scale, PUu}]
    __shared__ float  red2[2][NS * 17]; // 17408 B

    // ---- staging: c, U, and T2[bh] = sum_s c*U (one wave per 64 s) ----
    {
        int bh = t >> 7, s = t & 127;
        int b = b0 + bh;
        float uu = U[b * NS + s];
        float cv;
        if (first) {
            cv = mask[b * NS + s] * (1.f / 128.f);
        } else {
            cv = __expf(bl[(size_t)(b * NC + n) * NS + s] - mxg[b * NS + s])
                 * minvg[b * NS + s];
        }
        cs[s][bh] = cv;
        Us[s][bh] = uu;
        float p = cv * uu;
#pragma unroll
        for (int o = 32; o > 0; o >>= 1) p += __shfl_xor(p, o);
        if ((t & 63) == 0) tpar[bh][(t >> 6) & 1] = p;
    }

    // prefetch PE1 fragment for the squash tail (latency hides under pass 1)
    float4 p14;
    if (t < 32) p14 = ((const float4*)PE1)[n * 16 + (t & 15)];

    int dq = t & 15, sq = t >> 4;
    int s0 = sq * 8;
    // pe2 frequencies for (n, dq) — shared by both batches
    int k2 = n * 32 + dq * 2;
    float g0 = __expf(-L4 * (float)k2 * (1.f / 4096.f));
    float g1 = __expf(-L4 * (float)(k2 + 1) * (1.f / 4096.f));
    float sa = __sinf((float)s0 * g0), ca = __cosf((float)s0 * g0);
    float sb = __sinf((float)s0 * g1), cb = __cosf((float)s0 * g1);
    float sg0 = __sinf(g0), cg0 = __cosf(g0);
    float sg1 = __sinf(g1), cg1 = __cosf(g1);
    __syncthreads();

    // prefetch the 8 c-pairs for this thread's s-range (4x ds_read_b128)
    float4 cc4[4];
    {
        const float4* csp = (const float4*)&cs[s0][0];
        cc4[0] = csp[0]; cc4[1] = csp[1]; cc4[2] = csp[2]; cc4[3] = csp[3];
    }

    // ---- pass 1 ----
    const float4* M4a = (const float4*)(M + (size_t)(b0 * NS) * ND) + dq;
    const float4* M4b = M4a + NS * 16;
    float4 va[8], vb[8];
    float4 acc0 = make_float4(0.f, 0.f, 0.f, 0.f);
    float4 acc1 = make_float4(0.f, 0.f, 0.f, 0.f);
#pragma unroll
    for (int i = 0; i < 8; ++i) {
        int s = s0 + i;
        float4 m0 = M4a[s * 16];
        float4 m1 = M4b[s * 16];
        float2 cc = ((const float2*)cc4)[i];
        float4 u0, u1;
        u0.x = m0.x + sa; u0.y = m0.y + ca; u0.z = m0.z + sb; u0.w = m0.w + cb;
        u1.x = m1.x + sa; u1.y = m1.y + ca; u1.z = m1.z + sb; u1.w = m1.w + cb;
        va[i] = u0; vb[i] = u1;
        acc0.x = fmaf(cc.x, u0.x, acc0.x);
        acc0.y = fmaf(cc.x, u0.y, acc0.y);
        acc0.z = fmaf(cc.x, u0.z, acc0.z);
        acc0.w = fmaf(cc.x, u0.w, acc0.w);
        acc1.x = fmaf(cc.y, u1.x, acc1.x);
        acc1.y = fmaf(cc.y, u1.y, acc1.y);
        acc1.z = fmaf(cc.y, u1.z, acc1.z);
        acc1.w = fmaf(cc.y, u1.w, acc1.w);
        // rotate both frequency pairs to s+1
        float nsa = fmaf(sa, cg0, ca * sg0);
        float nca = fmaf(ca, cg0, -sa * sg0);
        sa = nsa; ca = nca;
        float nsb = fmaf(sb, cg1, cb * sg1);
        float ncb = fmaf(cb, cg1, -sb * sg1);
        sb = nsb; cb = ncb;
    }
    // reduce the 4 sq-chunks within each wave (lanes xor 16, 32)
#pragma unroll
    for (int o = 16; o <= 32; o <<= 1) {
        acc0.x += __shfl_xor(acc0.x, o); acc0.y += __shfl_xor(acc0.y, o);
        acc0.z += __shfl_xor(acc0.z, o); acc0.w += __shfl_xor(acc0.w, o);
        acc1.x += __shfl_xor(acc1.x, o); acc1.y += __shfl_xor(acc1.y, o);
        acc1.z += __shfl_xor(acc1.z, o); acc1.w += __shfl_xor(acc1.w, o);
    }
    if ((t & 48) == 0) {
        int w = t >> 6;
        redw[0][w][dq] = acc0;
        redw[1][w][dq] = acc1;
    }
    __syncthreads();

    // ---- combine + squash (wave 0, lanes 0-31: 16 lanes per bh) ----
    if (t < 32) {
        int bh = t >> 4, q = t & 15;
        float4 r0 = redw[bh][0][q], r1 = redw[bh][1][q];
        float4 r2 = redw[bh][2][q], r3 = redw[bh][3][q];
        float4 o;
        o.x = r0.x + r1.x + r2.x + r3.x;
        o.y = r0.y + r1.y + r2.y + r3.y;
        o.z = r0.z + r1.z + r2.z + r3.z;
        o.w = r0.w + r1.w + r2.w + r3.w;
        float T2 = tpar[bh][0] + tpar[bh][1];
        o.x = fmaf(p14.x, T2, o.x);
        o.y = fmaf(p14.y, T2, o.y);
        o.z = fmaf(p14.z, T2, o.z);
        o.w = fmaf(p14.w, T2, o.w);
        outs4[bh][q] = o;
        float ssq = o.x * o.x + o.y * o.y + o.z * o.z + o.w * o.w;
        float ppu = o.x * p14.x + o.y * p14.y + o.z * p14.z + o.w * p14.w;
#pragma unroll
        for (int o2 = 1; o2 <= 8; o2 <<= 1) {   // stays within 16-lane group
            ssq += __shfl_xor(ssq, o2);
            ppu += __shfl_xor(ppu, o2);
        }
        if (q == 0) {
            sc2[bh][0] = ssq / (1.f + ssq) * rsqrtf(ssq + 1e-7f);
            sc2[bh][1] = ppu;
        }
    }
    __syncthreads();

    if (last) {
        if (t < 32) {
            int bh = t >> 4, q = t & 15;
            float sc = sc2[bh][0];
            float4 o = outs4[bh][q];
            o.x *= sc; o.y *= sc; o.z *= sc; o.w *= sc;
            ((float4*)og)[((b0 + bh) * NC + n) * 16 + q] = o;
        }
        return;
    }

    // ---- pass 2: bl[s] = scale*(sum_d outp*(M+pe2) + PUu*U[s]) ----
    float4 oa = outs4[0][dq], ob = outs4[1][dq];
#pragma unroll
    for (int i = 0; i < 8; ++i) {
        int s = s0 + i;
        float4 v0 = va[i], v1 = vb[i];
        red2[0][s * 17 + dq] = v0.x * oa.x + v0.y * oa.y + v0.z * oa.z + v0.w * oa.w;
        red2[1][s * 17 + dq] = v1.x * ob.x + v1.y * ob.y + v1.z * ob.z + v1.w * ob.w;
    }
    __syncthreads();
    {
        int bh = t >> 7, s = t & 127;
        const float* r = &red2[bh][s * 17];
        float sum = 0.f;
#pragma unroll
        for (int q = 0; q < 16; ++q) sum += r[q];
        bl[((b0 + bh) * NC + n) * NS + s] =
            sc2[bh][0] * (sum + sc2[bh][1] * Us[s][bh]);
    }
}

// ---------------------------------------------------------------------------
extern "C" void kernel_launch(void* const* d_in, const int* in_sizes, int n_in,
                              void* d_out, int out_size, void* d_ws, size_t ws_size,
                              hipStream_t stream) {
    const float* u    = (const float*)d_in[0];  // (32,128,256)
    const float* mask = (const float*)d_in[1];  // (32,128)
    const float* W    = (const float*)d_in[2];  // (1,256,64)
    float* out = (float*)d_out;                 // (32,128,64) = [b][n][d]

    float* ws   = (float*)d_ws;
    float* M    = ws;                           // 262144
    float* U    = M + NB * NS * ND;             // 4096
    float* PE1  = U + NB * NS;                  // 8192
    float* bl   = PE1 + NC * ND;                // 524288  [b][n][s]
    float* mx   = bl + NB * NC * NS;            // 4096    [b][s]
    float* minv = mx + NB * NS;                 // 4096    [b][s]

    k_prep<<<288, 256, 0, stream>>>(u, W, M, U, PE1);

    // iter 0 (uniform c = mask/128) -> logits bl
    kR<<<2048, 256, 0, stream>>>(M, U, PE1, mx, minv, mask, out, bl, 1, 0);
    kRed<<<128, 256, 0, stream>>>(bl, mask, mx, minv);
    // iter 1: c = exp(bl-mx)*minv inline -> logits bl
    kR<<<2048, 256, 0, stream>>>(M, U, PE1, mx, minv, mask, out, bl, 0, 0);
    kRed<<<128, 256, 0, stream>>>(bl, mask, mx, minv);
    // iter 2 (final) -> d_out
    kR<<<2048, 256, 0, stream>>>(M, U, PE1, mx, minv, mask, out, bl, 0, 1);
}